// Round 2
// 319.688 us; speedup vs baseline: 1.0697x; 1.0697x over previous
//
#include <hip/hip_runtime.h>
#include <hip/hip_bf16.h>

// ssAttention fused kernel for MI355X (gfx950).
// Inputs fp32, OUTPUT fp32 (reference is an all-fp32 jnp pipeline).
// Internal compute: bf16 MFMA (16x16x32), fp32 accumulate; 2% relative gate.
// Decomposition: each pair position p=(a,b) owns a 16x128 slice (16 samples).
// One workgroup (4 waves) processes positions in a grid-stride loop:
//   LN -> Q,K,V,G proj (weights register-resident) -> per-head 16x16 attention
//   over samples -> gate -> out proj -> fp32 store.
//
// R1 (FAILED): __launch_bounds__(256,4) capped unified VGPR+AGPR at 128; the
//   160-reg weight arrays spilled to scratch -> 539us + numeric drift.
//   Lesson: occupancy is register-limited at ~250 unified regs; 2 blocks/CU
//   is the ceiling for the register-resident-weight strategy.
// R2: attack the per-iteration serial chain instead (13.7k cyc/iter vs ~1k
//   issued). (a) Phase D + outb_s removed: out-projection stores directly to
//   global (64B contiguous per quad). (b) Barriers 4 -> 2: with D gone,
//   lifetime analysis shows end-A and end-B barriers suffice (zn_s W@A/R@B,
//   ob_s W@B/R@C; cross-iteration hazards each covered by the other barrier).
//   (c) z for iteration t+1 prefetched into registers right after the end-A
//   barrier so its ~400-900 cyc latency hides under Phase B.

typedef short bf16x8 __attribute__((ext_vector_type(8)));
typedef float f32x4 __attribute__((ext_vector_type(4)));

#define MFMA16x32(A, B, C) __builtin_amdgcn_mfma_f32_16x16x32_bf16((A), (B), (C), 0, 0, 0)

__device__ __forceinline__ unsigned short f2bf(float f) {
    unsigned int u = __float_as_uint(f);
    u += 0x7fffu + ((u >> 16) & 1u);   // RTNE
    return (unsigned short)(u >> 16);
}

static constexpr int  DD     = 128;
static constexpr int  NPOS   = 128 * 128;            // 16384 pair positions
static constexpr long ZSTR   = (long)NPOS * DD;      // sample stride in elements
static constexpr int  ZN_STR = 136;  // padded stride (ushort) for 16x128 bf16 LDS bufs
static constexpr int  SB_STR = 56;   // padded stride (ushort) for 16x32 bf16 LDS bufs

__launch_bounds__(256, 2)
__global__ void ssattn_fused(const float* __restrict__ z,
                             const float* __restrict__ ln_w,
                             const float* __restrict__ ln_b,
                             const float* __restrict__ Wq,
                             const float* __restrict__ Wk,
                             const float* __restrict__ Wv,
                             const float* __restrict__ Wg,
                             const float* __restrict__ bg,
                             const float* __restrict__ Wo,
                             const float* __restrict__ bo,
                             float* __restrict__ out)
{
    __shared__ __align__(16) unsigned short zn_s[16 * ZN_STR];    // zn (bf16), A-readable
    __shared__ __align__(16) unsigned short ob_s[16 * ZN_STR];    // gated O (bf16), A-readable
    __shared__ __align__(16) unsigned short qb_s[4][16 * SB_STR]; // per-wave Q (then P), K=32 pad
    __shared__ __align__(16) unsigned short kq_s[4][16 * SB_STR]; // per-wave K
    __shared__ __align__(16) unsigned short vb_s[4][16 * SB_STR]; // per-wave V^T
    __shared__ float lnw_s[DD];
    __shared__ float lnb_s[DD];

    const int tid  = threadIdx.x;
    const int wid  = tid >> 6;     // wave 0..3 -> heads {2w, 2w+1}
    const int lane = tid & 63;
    const int quad = lane >> 4;
    const int lm   = lane & 15;
    const int r16  = tid >> 4;     // row 0..15 for LN phase
    const int s16  = tid & 15;

    // ---- one-time setup: LN params to LDS, zero K=32 pad scratch ----
    if (tid < DD) { lnw_s[tid] = ln_w[tid]; lnb_s[tid] = ln_b[tid]; }
    for (int i = tid; i < 16 * SB_STR; i += 256) {
        qb_s[0][i] = 0; qb_s[1][i] = 0; qb_s[2][i] = 0; qb_s[3][i] = 0;
        kq_s[0][i] = 0; kq_s[1][i] = 0; kq_s[2][i] = 0; kq_s[3][i] = 0;
        vb_s[0][i] = 0; vb_s[1][i] = 0; vb_s[2][i] = 0; vb_s[3][i] = 0;
    }

    // ---- register-resident weights (fp32 -> bf16): B-frag B[k=kb*32+quad*8+j][n=col] ----
    bf16x8 wq_r[2][4], wk_r[2][4], wv_r[2][4], wg_r[2][4], wo_r[2][4];
    float bg_r[2], bo_r[2];
#pragma unroll
    for (int hl = 0; hl < 2; ++hl) {
        const int col = (wid * 2 + hl) * 16 + lm;
        bg_r[hl] = bg[col];
        bo_r[hl] = bo[col];
#pragma unroll
        for (int kb = 0; kb < 4; ++kb) {
            const int kbase = kb * 32 + quad * 8;
            bf16x8 a, b, c, d, e;
#pragma unroll
            for (int j = 0; j < 8; ++j) {
                const int k = kbase + j;
                a[j] = (short)f2bf(Wq[k * DD + col]);
                b[j] = (short)f2bf(Wk[k * DD + col]);
                c[j] = (short)f2bf(Wv[k * DD + col]);
                d[j] = (short)f2bf(Wg[k * DD + col]);
                e[j] = (short)f2bf(Wo[k * DD + col]);
            }
            wq_r[hl][kb] = a; wk_r[hl][kb] = b; wv_r[hl][kb] = c;
            wg_r[hl][kb] = d; wo_r[hl][kb] = e;
        }
    }
    __syncthreads();

    unsigned short* const qb = qb_s[wid];
    unsigned short* const kq = kq_s[wid];
    unsigned short* const vb = vb_s[wid];

    // ---- prologue: load first z-tile into registers ----
    int p = blockIdx.x;
    float4 cura, curb;
    {
        const float* zp = z + (long)r16 * ZSTR + (long)p * DD + s16 * 8;
        cura = *(const float4*)zp;
        curb = *(const float4*)(zp + 4);
    }

    for (; p < NPOS; p += gridDim.x) {
        // ---- Phase A: LayerNorm 16 z-rows (registers preloaded), store zn (bf16) ----
        {
            float x[8] = {cura.x, cura.y, cura.z, cura.w, curb.x, curb.y, curb.z, curb.w};
            float s = 0.f, ss = 0.f;
#pragma unroll
            for (int j = 0; j < 8; ++j) { s += x[j]; ss += x[j] * x[j]; }
#pragma unroll
            for (int m = 1; m <= 8; m <<= 1) {
                s  += __shfl_xor(s,  m, 16);
                ss += __shfl_xor(ss, m, 16);
            }
            const float mu = s * (1.f / 128.f);
            const float rs = rsqrtf(ss * (1.f / 128.f) - mu * mu + 1e-5f);
            unsigned int pk[4];
#pragma unroll
            for (int jj = 0; jj < 4; ++jj) {
                const int c0 = s16 * 8 + jj * 2;
                const unsigned short lo = f2bf((x[jj * 2]     - mu) * rs * lnw_s[c0]     + lnb_s[c0]);
                const unsigned short hi = f2bf((x[jj * 2 + 1] - mu) * rs * lnw_s[c0 + 1] + lnb_s[c0 + 1]);
                pk[jj] = (unsigned)lo | ((unsigned)hi << 16);
            }
            uint4 st; st.x = pk[0]; st.y = pk[1]; st.z = pk[2]; st.w = pk[3];
            *(uint4*)&zn_s[r16 * ZN_STR + s16 * 8] = st;
        }
        __syncthreads();   // end-A: zn_s visible; also orders prev-C ob_s reads vs this-B writes

        // ---- prefetch next iteration's z-tile (latency hides under Phase B) ----
        {
            const int pn  = p + gridDim.x;
            const int pnc = (pn < NPOS) ? pn : p;   // clamped; dead on last iter
            const float* zp2 = z + (long)r16 * ZSTR + (long)pnc * DD + s16 * 8;
            cura = *(const float4*)zp2;
            curb = *(const float4*)(zp2 + 4);
        }

        // ---- Phase B: projections (MFMA) + per-head attention ----
        bf16x8 af[4];  // A-frags of zn (A[m=lm][k=kb*32+quad*8+j])
#pragma unroll
        for (int kb = 0; kb < 4; ++kb)
            af[kb] = *(const bf16x8*)&zn_s[lm * ZN_STR + kb * 32 + quad * 8];

#pragma unroll
        for (int hl = 0; hl < 2; ++hl) {
            f32x4 aq = {0,0,0,0}, ak = {0,0,0,0}, av = {0,0,0,0}, ag = {0,0,0,0};
#pragma unroll
            for (int kb = 0; kb < 4; ++kb) {
                aq = MFMA16x32(af[kb], wq_r[hl][kb], aq);
                ak = MFMA16x32(af[kb], wk_r[hl][kb], ak);
                av = MFMA16x32(af[kb], wv_r[hl][kb], av);
                ag = MFMA16x32(af[kb], wg_r[hl][kb], ag);
            }
            // C/D layout: row = quad*4+r, col = lm.  Scale 1/sqrt(16) folded into Q.
#pragma unroll
            for (int r = 0; r < 4; ++r) {
                const int row = quad * 4 + r;
                qb[row * SB_STR + lm] = f2bf(aq[r] * 0.25f);  // Q[i][c]
                kq[row * SB_STR + lm] = f2bf(ak[r]);          // K[j][c]
                vb[lm * SB_STR + row] = f2bf(av[r]);          // V^T[c][j]
            }
            float gv[4];
#pragma unroll
            for (int r = 0; r < 4; ++r)
                gv[r] = 1.f / (1.f + __expf(-(ag[r] + bg_r[hl])));

            // att = (Q/4) @ K^T. K-dim (=C=16) zero-padded to 32.
            const bf16x8 aqf = *(const bf16x8*)&qb[lm * SB_STR + quad * 8];
            const bf16x8 bkf = *(const bf16x8*)&kq[lm * SB_STR + quad * 8];
            const f32x4 z4 = {0,0,0,0};
            f32x4 att = MFMA16x32(aqf, bkf, z4);

            // softmax over j (= C/D col = lm across the 16 lanes of this quad)
            f32x4 pr;
#pragma unroll
            for (int r = 0; r < 4; ++r) {
                const float a = att[r];
                float mx = a;
#pragma unroll
                for (int m = 1; m <= 8; m <<= 1) mx = fmaxf(mx, __shfl_xor(mx, m, 16));
                const float ex = __expf(a - mx);
                float sm = ex;
#pragma unroll
                for (int m = 1; m <= 8; m <<= 1) sm += __shfl_xor(sm, m, 16);
                pr[r] = ex / sm;
            }
            // P overwrites Q buffer (Q frags already consumed; same-wave DS ops in-order)
#pragma unroll
            for (int r = 0; r < 4; ++r)
                qb[(quad * 4 + r) * SB_STR + lm] = f2bf(pr[r]);

            // O = P @ V : A-frag of P, B-frag from V^T rows (contiguous k=j)
            const bf16x8 apf = *(const bf16x8*)&qb[lm * SB_STR + quad * 8];
            const bf16x8 bvf = *(const bf16x8*)&vb[lm * SB_STR + quad * 8];
            f32x4 oc = MFMA16x32(apf, bvf, z4);

            const int hcol = (wid * 2 + hl) * 16 + lm;
#pragma unroll
            for (int r = 0; r < 4; ++r)
                ob_s[(quad * 4 + r) * ZN_STR + hcol] = f2bf(oc[r] * gv[r]);
        }
        __syncthreads();   // end-B: ob_s visible; also orders this-B zn_s reads vs next-A writes

        // ---- Phase C: out = O @ Wo + bo, stored DIRECTLY to global ----
        bf16x8 of[4];
#pragma unroll
        for (int kb = 0; kb < 4; ++kb)
            of[kb] = *(const bf16x8*)&ob_s[lm * ZN_STR + kb * 32 + quad * 8];
        float* const op0 = out + (long)p * DD + (long)(quad * 4) * ZSTR;
#pragma unroll
        for (int hl = 0; hl < 2; ++hl) {
            f32x4 acc = {0,0,0,0};
#pragma unroll
            for (int kb = 0; kb < 4; ++kb)
                acc = MFMA16x32(of[kb], wo_r[hl][kb], acc);
            const int col = (wid * 2 + hl) * 16 + lm;
#pragma unroll
            for (int r = 0; r < 4; ++r)
                op0[(long)r * ZSTR + col] = acc[r] + bo_r[hl];  // 64B contiguous per quad
        }
        // no barrier here: next-iter zn_s write is covered by end-B barrier;
        // next-iter ob_s write (in B) is covered by next end-A barrier.
    }
}

extern "C" void kernel_launch(void* const* d_in, const int* in_sizes, int n_in,
                              void* d_out, int out_size, void* d_ws, size_t ws_size,
                              hipStream_t stream) {
    (void)in_sizes; (void)n_in; (void)out_size; (void)d_ws; (void)ws_size;
    // 512 blocks = 2 blocks/CU (unified-regfile-limited); 16384/512 = 32
    // positions per block (uniform).
    ssattn_fused<<<dim3(512), dim3(256), 0, stream>>>(
        (const float*)d_in[0],  // z
        (const float*)d_in[1],  // ln_w
        (const float*)d_in[2],  // ln_b
        (const float*)d_in[3],  // Wq
        (const float*)d_in[4],  // Wk
        (const float*)d_in[5],  // Wv
        (const float*)d_in[6],  // Wg
        (const float*)d_in[7],  // bg
        (const float*)d_in[8],  // Wo
        (const float*)d_in[9],  // bo
        (float*)d_out);
}

// Round 5
// 294.717 us; speedup vs baseline: 1.1604x; 1.0847x over previous
//
#include <hip/hip_runtime.h>
#include <hip/hip_bf16.h>

// ssAttention fused kernel for MI355X (gfx950).
// Inputs fp32, OUTPUT fp32 (reference is an all-fp32 jnp pipeline).
// Internal compute: bf16 MFMA (16x16x32), fp32 accumulate; 2% relative gate.
// Decomposition: each pair position p=(a,b) owns a 16x128 slice (16 samples).
// One workgroup (4 waves) processes positions in a grid-stride loop:
//   LN -> Q,K,V,G proj (weights register-resident) -> per-head 16x16 attention
//   over samples -> gate -> out proj -> fp32 store.
//
// R1 (FAILED): __launch_bounds__(256,4) capped unified VGPR+AGPR at 128 ->
//   weight arrays spilled -> 539us + numeric drift. 2 blocks/CU is the
//   ceiling for the register-resident-weight strategy.
// R2 (NEUTRAL, 183->177us/dispatch): Phase D + 2 barriers removed, z prefetch.
// R3 (COMPILE FAIL): update_dpp ctrl must be a call-site constant.
// R4 (PERF WIN, NUMERIC FAIL): DPP reductions bought ~15% (dispatch ~150us)
//   but v_rcp_f32 in softmax-norm + sigmoid grew pre-absmax 3.97e-4->5.72e-4;
//   harness post-timing check runs ~1.4-1.6x hotter -> 9.0e-4 > 7.2e-4 fail.
//   Lesson: pre-absmax budget is ~5e-4; rcp's 1-ulp error flips bf16
//   roundings across 16M outputs.
// R5: keep DPP butterflies (bitwise-identical to the shfl_xor chain:
//   IEEE add is bitwise-commutative and post-stage-2 quad lanes are equal,
//   so mirror-perm sources feed identical bits); restore exact IEEE division
//   for softmax normalization and sigmoid. Expect R2 numerics bit-for-bit
//   with R4's latency win.

typedef short bf16x8 __attribute__((ext_vector_type(8)));
typedef float f32x4 __attribute__((ext_vector_type(4)));

#define MFMA16x32(A, B, C) __builtin_amdgcn_mfma_f32_16x16x32_bf16((A), (B), (C), 0, 0, 0)

__device__ __forceinline__ unsigned short f2bf(float f) {
    unsigned int u = __float_as_uint(f);
    u += 0x7fffu + ((u >> 16) & 1u);   // RTNE
    return (unsigned short)(u >> 16);
}

// ---- 16-lane (DPP-row) reductions, pure VALU ----
template <int CTRL>
__device__ __forceinline__ float dpp_mov16(float x) {
    return __int_as_float(__builtin_amdgcn_update_dpp(
        0, __float_as_int(x), CTRL, 0xf, 0xf, true));
}
// after each stage every lane of the combined sub-group holds the same
// partial, so mirror perms substitute for xor4/xor8 (bitwise-identical).
__device__ __forceinline__ float red16_sum(float x) {
    x += dpp_mov16<0xB1>(x);   // quad_perm [1,0,3,2]  (xor 1)
    x += dpp_mov16<0x4E>(x);   // quad_perm [2,3,0,1]  (xor 2)
    x += dpp_mov16<0x141>(x);  // row_half_mirror      (crosses quads in 8)
    x += dpp_mov16<0x140>(x);  // row_mirror           (crosses 8s in 16)
    return x;
}
__device__ __forceinline__ float red16_max(float x) {
    x = fmaxf(x, dpp_mov16<0xB1>(x));
    x = fmaxf(x, dpp_mov16<0x4E>(x));
    x = fmaxf(x, dpp_mov16<0x141>(x));
    x = fmaxf(x, dpp_mov16<0x140>(x));
    return x;
}

static constexpr int  DD     = 128;
static constexpr int  NPOS   = 128 * 128;            // 16384 pair positions
static constexpr long ZSTR   = (long)NPOS * DD;      // sample stride in elements
static constexpr int  ZN_STR = 136;  // padded stride (ushort) for 16x128 bf16 LDS bufs
static constexpr int  SB_STR = 56;   // padded stride (ushort) for 16x32 bf16 LDS bufs

__launch_bounds__(256, 2)
__global__ void ssattn_fused(const float* __restrict__ z,
                             const float* __restrict__ ln_w,
                             const float* __restrict__ ln_b,
                             const float* __restrict__ Wq,
                             const float* __restrict__ Wk,
                             const float* __restrict__ Wv,
                             const float* __restrict__ Wg,
                             const float* __restrict__ bg,
                             const float* __restrict__ Wo,
                             const float* __restrict__ bo,
                             float* __restrict__ out)
{
    __shared__ __align__(16) unsigned short zn_s[16 * ZN_STR];    // zn (bf16), A-readable
    __shared__ __align__(16) unsigned short ob_s[16 * ZN_STR];    // gated O (bf16), A-readable
    __shared__ __align__(16) unsigned short qb_s[4][16 * SB_STR]; // per-wave Q (then P), K=32 pad
    __shared__ __align__(16) unsigned short kq_s[4][16 * SB_STR]; // per-wave K
    __shared__ __align__(16) unsigned short vb_s[4][16 * SB_STR]; // per-wave V^T
    __shared__ float lnw_s[DD];
    __shared__ float lnb_s[DD];

    const int tid  = threadIdx.x;
    const int wid  = tid >> 6;     // wave 0..3 -> heads {2w, 2w+1}
    const int lane = tid & 63;
    const int quad = lane >> 4;
    const int lm   = lane & 15;
    const int r16  = tid >> 4;     // row 0..15 for LN phase
    const int s16  = tid & 15;

    // ---- one-time setup: LN params to LDS, zero K=32 pad scratch ----
    if (tid < DD) { lnw_s[tid] = ln_w[tid]; lnb_s[tid] = ln_b[tid]; }
    for (int i = tid; i < 16 * SB_STR; i += 256) {
        qb_s[0][i] = 0; qb_s[1][i] = 0; qb_s[2][i] = 0; qb_s[3][i] = 0;
        kq_s[0][i] = 0; kq_s[1][i] = 0; kq_s[2][i] = 0; kq_s[3][i] = 0;
        vb_s[0][i] = 0; vb_s[1][i] = 0; vb_s[2][i] = 0; vb_s[3][i] = 0;
    }

    // ---- register-resident weights (fp32 -> bf16): B-frag B[k=kb*32+quad*8+j][n=col] ----
    bf16x8 wq_r[2][4], wk_r[2][4], wv_r[2][4], wg_r[2][4], wo_r[2][4];
    float bg_r[2], bo_r[2];
#pragma unroll
    for (int hl = 0; hl < 2; ++hl) {
        const int col = (wid * 2 + hl) * 16 + lm;
        bg_r[hl] = bg[col];
        bo_r[hl] = bo[col];
#pragma unroll
        for (int kb = 0; kb < 4; ++kb) {
            const int kbase = kb * 32 + quad * 8;
            bf16x8 a, b, c, d, e;
#pragma unroll
            for (int j = 0; j < 8; ++j) {
                const int k = kbase + j;
                a[j] = (short)f2bf(Wq[k * DD + col]);
                b[j] = (short)f2bf(Wk[k * DD + col]);
                c[j] = (short)f2bf(Wv[k * DD + col]);
                d[j] = (short)f2bf(Wg[k * DD + col]);
                e[j] = (short)f2bf(Wo[k * DD + col]);
            }
            wq_r[hl][kb] = a; wk_r[hl][kb] = b; wv_r[hl][kb] = c;
            wg_r[hl][kb] = d; wo_r[hl][kb] = e;
        }
    }
    __syncthreads();

    unsigned short* const qb = qb_s[wid];
    unsigned short* const kq = kq_s[wid];
    unsigned short* const vb = vb_s[wid];

    // ---- prologue: load first z-tile into registers ----
    int p = blockIdx.x;
    float4 cura, curb;
    {
        const float* zp = z + (long)r16 * ZSTR + (long)p * DD + s16 * 8;
        cura = *(const float4*)zp;
        curb = *(const float4*)(zp + 4);
    }

    for (; p < NPOS; p += gridDim.x) {
        // ---- Phase A: LayerNorm 16 z-rows (registers preloaded), store zn (bf16) ----
        {
            float x[8] = {cura.x, cura.y, cura.z, cura.w, curb.x, curb.y, curb.z, curb.w};
            float s = 0.f, ss = 0.f;
#pragma unroll
            for (int j = 0; j < 8; ++j) { s += x[j]; ss += x[j] * x[j]; }
            s  = red16_sum(s);
            ss = red16_sum(ss);
            const float mu = s * (1.f / 128.f);
            const float rs = rsqrtf(ss * (1.f / 128.f) - mu * mu + 1e-5f);
            unsigned int pk[4];
#pragma unroll
            for (int jj = 0; jj < 4; ++jj) {
                const int c0 = s16 * 8 + jj * 2;
                const unsigned short lo = f2bf((x[jj * 2]     - mu) * rs * lnw_s[c0]     + lnb_s[c0]);
                const unsigned short hi = f2bf((x[jj * 2 + 1] - mu) * rs * lnw_s[c0 + 1] + lnb_s[c0 + 1]);
                pk[jj] = (unsigned)lo | ((unsigned)hi << 16);
            }
            uint4 st; st.x = pk[0]; st.y = pk[1]; st.z = pk[2]; st.w = pk[3];
            *(uint4*)&zn_s[r16 * ZN_STR + s16 * 8] = st;
        }
        __syncthreads();   // end-A: zn_s visible; also orders prev-C ob_s reads vs this-B writes

        // ---- prefetch next iteration's z-tile (latency hides under Phase B) ----
        {
            const int pn  = p + gridDim.x;
            const int pnc = (pn < NPOS) ? pn : p;   // clamped; dead on last iter
            const float* zp2 = z + (long)r16 * ZSTR + (long)pnc * DD + s16 * 8;
            cura = *(const float4*)zp2;
            curb = *(const float4*)(zp2 + 4);
        }

        // ---- Phase B: projections (MFMA) + per-head attention ----
        bf16x8 af[4];  // A-frags of zn (A[m=lm][k=kb*32+quad*8+j])
#pragma unroll
        for (int kb = 0; kb < 4; ++kb)
            af[kb] = *(const bf16x8*)&zn_s[lm * ZN_STR + kb * 32 + quad * 8];

#pragma unroll
        for (int hl = 0; hl < 2; ++hl) {
            f32x4 aq = {0,0,0,0}, ak = {0,0,0,0}, av = {0,0,0,0}, ag = {0,0,0,0};
#pragma unroll
            for (int kb = 0; kb < 4; ++kb) {
                aq = MFMA16x32(af[kb], wq_r[hl][kb], aq);
                ak = MFMA16x32(af[kb], wk_r[hl][kb], ak);
                av = MFMA16x32(af[kb], wv_r[hl][kb], av);
                ag = MFMA16x32(af[kb], wg_r[hl][kb], ag);
            }
            // C/D layout: row = quad*4+r, col = lm.  Scale 1/sqrt(16) folded into Q.
#pragma unroll
            for (int r = 0; r < 4; ++r) {
                const int row = quad * 4 + r;
                qb[row * SB_STR + lm] = f2bf(aq[r] * 0.25f);  // Q[i][c]
                kq[row * SB_STR + lm] = f2bf(ak[r]);          // K[j][c]
                vb[lm * SB_STR + row] = f2bf(av[r]);          // V^T[c][j]
            }
            float gv[4];
#pragma unroll
            for (int r = 0; r < 4; ++r)
                gv[r] = 1.f / (1.f + __expf(-(ag[r] + bg_r[hl])));

            // att = (Q/4) @ K^T. K-dim (=C=16) zero-padded to 32.
            const bf16x8 aqf = *(const bf16x8*)&qb[lm * SB_STR + quad * 8];
            const bf16x8 bkf = *(const bf16x8*)&kq[lm * SB_STR + quad * 8];
            const f32x4 z4 = {0,0,0,0};
            f32x4 att = MFMA16x32(aqf, bkf, z4);

            // softmax over j (= C/D col = lm across the 16 lanes of this quad)
            f32x4 pr;
#pragma unroll
            for (int r = 0; r < 4; ++r) {
                const float a  = att[r];
                const float mx = red16_max(a);
                const float ex = __expf(a - mx);
                const float sm = red16_sum(ex);
                pr[r] = ex / sm;
            }
            // P overwrites Q buffer (Q frags already consumed; same-wave DS ops in-order)
#pragma unroll
            for (int r = 0; r < 4; ++r)
                qb[(quad * 4 + r) * SB_STR + lm] = f2bf(pr[r]);

            // O = P @ V : A-frag of P, B-frag from V^T rows (contiguous k=j)
            const bf16x8 apf = *(const bf16x8*)&qb[lm * SB_STR + quad * 8];
            const bf16x8 bvf = *(const bf16x8*)&vb[lm * SB_STR + quad * 8];
            f32x4 oc = MFMA16x32(apf, bvf, z4);

            const int hcol = (wid * 2 + hl) * 16 + lm;
#pragma unroll
            for (int r = 0; r < 4; ++r)
                ob_s[(quad * 4 + r) * ZN_STR + hcol] = f2bf(oc[r] * gv[r]);
        }
        __syncthreads();   // end-B: ob_s visible; also orders this-B zn_s reads vs next-A writes

        // ---- Phase C: out = O @ Wo + bo, stored DIRECTLY to global ----
        bf16x8 of[4];
#pragma unroll
        for (int kb = 0; kb < 4; ++kb)
            of[kb] = *(const bf16x8*)&ob_s[lm * ZN_STR + kb * 32 + quad * 8];
        float* const op0 = out + (long)p * DD + (long)(quad * 4) * ZSTR;
#pragma unroll
        for (int hl = 0; hl < 2; ++hl) {
            f32x4 acc = {0,0,0,0};
#pragma unroll
            for (int kb = 0; kb < 4; ++kb)
                acc = MFMA16x32(of[kb], wo_r[hl][kb], acc);
            const int col = (wid * 2 + hl) * 16 + lm;
#pragma unroll
            for (int r = 0; r < 4; ++r)
                op0[(long)r * ZSTR + col] = acc[r] + bo_r[hl];  // 64B contiguous per quad
        }
        // no barrier here: next-iter zn_s write is covered by end-B barrier;
        // next-iter ob_s write (in B) is covered by next end-A barrier.
    }
}

extern "C" void kernel_launch(void* const* d_in, const int* in_sizes, int n_in,
                              void* d_out, int out_size, void* d_ws, size_t ws_size,
                              hipStream_t stream) {
    (void)in_sizes; (void)n_in; (void)out_size; (void)d_ws; (void)ws_size;
    // 512 blocks = 2 blocks/CU (unified-regfile-limited); 16384/512 = 32
    // positions per block (uniform).
    ssattn_fused<<<dim3(512), dim3(256), 0, stream>>>(
        (const float*)d_in[0],  // z
        (const float*)d_in[1],  // ln_w
        (const float*)d_in[2],  // ln_b
        (const float*)d_in[3],  // Wq
        (const float*)d_in[4],  // Wk
        (const float*)d_in[5],  // Wv
        (const float*)d_in[6],  // Wg
        (const float*)d_in[7],  // bg
        (const float*)d_in[8],  // Wo
        (const float*)d_in[9],  // bo
        (float*)d_out);
}

// Round 6
// 293.783 us; speedup vs baseline: 1.1641x; 1.0032x over previous
//
#include <hip/hip_runtime.h>
#include <hip/hip_bf16.h>

// ssAttention fused kernel for MI355X (gfx950).
// Inputs fp32, OUTPUT fp32 (reference is an all-fp32 jnp pipeline).
// Internal compute: bf16 MFMA (16x16x32), fp32 accumulate; 2% relative gate.
// Decomposition: each pair position p=(a,b) owns a 16x128 slice (16 samples).
// One workgroup (4 waves) processes TWO positions per grid-stride iteration:
//   LN -> Q,K,V,G proj (weights register-resident) -> per-head 16x16 attention
//   over samples -> gate -> out proj -> fp32 store.
//
// R1 (FAILED): launch_bounds(256,4) capped unified regs at 128 -> weight
//   spill -> 539us. 2 blocks/CU is the ceiling for register-resident weights.
// R2 (NEUTRAL, 183->177us/dispatch): Phase D + 2 barriers removed, z prefetch.
// R3 (COMPILE FAIL): update_dpp ctrl must be a call-site constant.
// R4 (PERF WIN, NUMERIC FAIL): DPP reductions ~15% faster but v_rcp_f32 grew
//   pre-absmax 3.97e-4 -> 5.72e-4; post-timing check runs ~1.5x hotter ->
//   fail. Lesson: pre-absmax budget ~5e-4; no approximate ops.
// R5 (WIN, 177->133.5us/dispatch): DPP butterflies + exact IEEE division.
//   Counters: VALU 58%, MFMA 15%, ~27% idle, HBM 19%. VALU+latency bound.
// R6: (a) deferred softmax normalization: write UNNORMALIZED P~=exp(a-mx) to
//   LDS right after exp; fold 1/sum into the gate scale 1/((1+e^-g)*sm) ->
//   16 divides/position -> 8, and the PV LDS round-trip overlaps the
//   sum-reduce+div instead of serializing behind it. 1/sqrt(C) folded into
//   the Wq bf16 load (exact exponent shift, bit-identical Q).
//   (b) 2-position batching per iteration: 4 independent (pos,head-pair)
//   chains in Phase B fill the ~27% idle; barriers halve per position.
//   LDS 60KB/block (120KB/CU ok). Watch VGPR (cap 256 unified) for spill.

typedef short bf16x8 __attribute__((ext_vector_type(8)));
typedef float f32x4 __attribute__((ext_vector_type(4)));

#define MFMA16x32(A, B, C) __builtin_amdgcn_mfma_f32_16x16x32_bf16((A), (B), (C), 0, 0, 0)

__device__ __forceinline__ unsigned short f2bf(float f) {
    unsigned int u = __float_as_uint(f);
    u += 0x7fffu + ((u >> 16) & 1u);   // RTNE
    return (unsigned short)(u >> 16);
}

// ---- 16-lane (DPP-row) reductions, pure VALU ----
template <int CTRL>
__device__ __forceinline__ float dpp_mov16(float x) {
    return __int_as_float(__builtin_amdgcn_update_dpp(
        0, __float_as_int(x), CTRL, 0xf, 0xf, true));
}
// after each stage every lane of the combined sub-group holds the same
// partial, so mirror perms substitute for xor4/xor8 (bitwise-identical).
__device__ __forceinline__ float red16_sum(float x) {
    x += dpp_mov16<0xB1>(x);   // quad_perm [1,0,3,2]  (xor 1)
    x += dpp_mov16<0x4E>(x);   // quad_perm [2,3,0,1]  (xor 2)
    x += dpp_mov16<0x141>(x);  // row_half_mirror      (crosses quads in 8)
    x += dpp_mov16<0x140>(x);  // row_mirror           (crosses 8s in 16)
    return x;
}
__device__ __forceinline__ float red16_max(float x) {
    x = fmaxf(x, dpp_mov16<0xB1>(x));
    x = fmaxf(x, dpp_mov16<0x4E>(x));
    x = fmaxf(x, dpp_mov16<0x141>(x));
    x = fmaxf(x, dpp_mov16<0x140>(x));
    return x;
}

static constexpr int  DD     = 128;
static constexpr int  NPOS   = 128 * 128;            // 16384 pair positions
static constexpr int  NPAIR  = NPOS / 2;             // 8192 position pairs
static constexpr long ZSTR   = (long)NPOS * DD;      // sample stride in elements
static constexpr int  ZN_STR = 136;  // padded stride (ushort) for 16x128 bf16 LDS bufs
static constexpr int  SB_STR = 56;   // padded stride (ushort) for 16x32 bf16 LDS bufs

__launch_bounds__(256, 2)
__global__ void ssattn_fused(const float* __restrict__ z,
                             const float* __restrict__ ln_w,
                             const float* __restrict__ ln_b,
                             const float* __restrict__ Wq,
                             const float* __restrict__ Wk,
                             const float* __restrict__ Wv,
                             const float* __restrict__ Wg,
                             const float* __restrict__ bg,
                             const float* __restrict__ Wo,
                             const float* __restrict__ bo,
                             float* __restrict__ out)
{
    __shared__ __align__(16) unsigned short zn_s[2][16 * ZN_STR];    // zn (bf16)
    __shared__ __align__(16) unsigned short ob_s[2][16 * ZN_STR];    // gated O (bf16)
    __shared__ __align__(16) unsigned short qb_s[4][2][16 * SB_STR]; // per-wave/pos Q->P~
    __shared__ __align__(16) unsigned short kq_s[4][2][16 * SB_STR]; // per-wave/pos K
    __shared__ __align__(16) unsigned short vb_s[4][2][16 * SB_STR]; // per-wave/pos V^T
    __shared__ float lnw_s[DD];
    __shared__ float lnb_s[DD];

    const int tid  = threadIdx.x;
    const int wid  = tid >> 6;     // wave 0..3 -> heads {2w, 2w+1}
    const int lane = tid & 63;
    const int quad = lane >> 4;
    const int lm   = lane & 15;
    const int r16  = tid >> 4;     // row 0..15 for LN phase
    const int s16  = tid & 15;

    // ---- one-time setup: LN params to LDS, zero K=32 pad scratch ----
    if (tid < DD) { lnw_s[tid] = ln_w[tid]; lnb_s[tid] = ln_b[tid]; }
    for (int i = tid; i < 4 * 2 * 16 * SB_STR; i += 256) {
        ((unsigned short*)qb_s)[i] = 0;
        ((unsigned short*)kq_s)[i] = 0;
        ((unsigned short*)vb_s)[i] = 0;
    }

    // ---- register-resident weights (fp32 -> bf16): B-frag B[k=kb*32+quad*8+j][n=col]
    //      Wq pre-scaled by 1/sqrt(C)=0.25 (exact exponent shift in bf16). ----
    bf16x8 wq_r[2][4], wk_r[2][4], wv_r[2][4], wg_r[2][4], wo_r[2][4];
    float bg_r[2], bo_r[2];
#pragma unroll
    for (int hl = 0; hl < 2; ++hl) {
        const int col = (wid * 2 + hl) * 16 + lm;
        bg_r[hl] = bg[col];
        bo_r[hl] = bo[col];
#pragma unroll
        for (int kb = 0; kb < 4; ++kb) {
            const int kbase = kb * 32 + quad * 8;
            bf16x8 a, b, c, d, e;
#pragma unroll
            for (int j = 0; j < 8; ++j) {
                const int k = kbase + j;
                a[j] = (short)f2bf(Wq[k * DD + col] * 0.25f);
                b[j] = (short)f2bf(Wk[k * DD + col]);
                c[j] = (short)f2bf(Wv[k * DD + col]);
                d[j] = (short)f2bf(Wg[k * DD + col]);
                e[j] = (short)f2bf(Wo[k * DD + col]);
            }
            wq_r[hl][kb] = a; wk_r[hl][kb] = b; wv_r[hl][kb] = c;
            wg_r[hl][kb] = d; wo_r[hl][kb] = e;
        }
    }
    __syncthreads();

    // ---- prologue: load first position-pair's z (p0=2*idx, p1 adjacent) ----
    int idx = blockIdx.x;
    float4 cA[2], cB[2];
    {
        const float* zp = z + (long)r16 * ZSTR + (long)(2 * idx) * DD + s16 * 8;
        cA[0] = *(const float4*)zp;        cB[0] = *(const float4*)(zp + 4);
        cA[1] = *(const float4*)(zp + DD); cB[1] = *(const float4*)(zp + DD + 4);
    }

    for (; idx < NPAIR; idx += gridDim.x) {
        const long pbase = (long)(2 * idx) * DD;

        // ---- Phase A: LayerNorm both position tiles, store zn (bf16) ----
#pragma unroll
        for (int pp = 0; pp < 2; ++pp) {
            float x[8] = {cA[pp].x, cA[pp].y, cA[pp].z, cA[pp].w,
                          cB[pp].x, cB[pp].y, cB[pp].z, cB[pp].w};
            float s = 0.f, ss = 0.f;
#pragma unroll
            for (int j = 0; j < 8; ++j) { s += x[j]; ss += x[j] * x[j]; }
            s  = red16_sum(s);
            ss = red16_sum(ss);
            const float mu = s * (1.f / 128.f);
            const float rs = rsqrtf(ss * (1.f / 128.f) - mu * mu + 1e-5f);
            unsigned int pk[4];
#pragma unroll
            for (int jj = 0; jj < 4; ++jj) {
                const int c0 = s16 * 8 + jj * 2;
                const unsigned short lo = f2bf((x[jj * 2]     - mu) * rs * lnw_s[c0]     + lnb_s[c0]);
                const unsigned short hi = f2bf((x[jj * 2 + 1] - mu) * rs * lnw_s[c0 + 1] + lnb_s[c0 + 1]);
                pk[jj] = (unsigned)lo | ((unsigned)hi << 16);
            }
            uint4 st; st.x = pk[0]; st.y = pk[1]; st.z = pk[2]; st.w = pk[3];
            *(uint4*)&zn_s[pp][r16 * ZN_STR + s16 * 8] = st;
        }
        __syncthreads();   // end-A: zn visible; orders prev-C ob reads vs this-B writes

        // ---- prefetch next pair's z (latency hides under Phase B) ----
        {
            const int ni = idx + gridDim.x;
            const int nc = (ni < NPAIR) ? ni : idx;   // clamped; dead on last iter
            const float* zp2 = z + (long)r16 * ZSTR + (long)(2 * nc) * DD + s16 * 8;
            cA[0] = *(const float4*)zp2;        cB[0] = *(const float4*)(zp2 + 4);
            cA[1] = *(const float4*)(zp2 + DD); cB[1] = *(const float4*)(zp2 + DD + 4);
        }

        // ---- Phase B: projections + attention, 4 independent (pp,hl) chains ----
#pragma unroll
        for (int pp = 0; pp < 2; ++pp) {
            unsigned short* const qbp = qb_s[wid][pp];
            unsigned short* const kqp = kq_s[wid][pp];
            unsigned short* const vbp = vb_s[wid][pp];

            bf16x8 af[4];  // A-frags of zn (A[m=lm][k=kb*32+quad*8+j])
#pragma unroll
            for (int kb = 0; kb < 4; ++kb)
                af[kb] = *(const bf16x8*)&zn_s[pp][lm * ZN_STR + kb * 32 + quad * 8];

#pragma unroll
            for (int hl = 0; hl < 2; ++hl) {
                f32x4 aq = {0,0,0,0}, ak = {0,0,0,0}, av = {0,0,0,0}, ag = {0,0,0,0};
#pragma unroll
                for (int kb = 0; kb < 4; ++kb) {
                    aq = MFMA16x32(af[kb], wq_r[hl][kb], aq);
                    ak = MFMA16x32(af[kb], wk_r[hl][kb], ak);
                    av = MFMA16x32(af[kb], wv_r[hl][kb], av);
                    ag = MFMA16x32(af[kb], wg_r[hl][kb], ag);
                }
                // C/D layout: row = quad*4+r, col = lm. (1/sqrt(C) already in Wq.)
#pragma unroll
                for (int r = 0; r < 4; ++r) {
                    const int row = quad * 4 + r;
                    qbp[row * SB_STR + lm] = f2bf(aq[r]);   // Q[i][c]
                    kqp[row * SB_STR + lm] = f2bf(ak[r]);   // K[j][c]
                    vbp[lm * SB_STR + row] = f2bf(av[r]);   // V^T[c][j]
                }
                float eg[4];
#pragma unroll
                for (int r = 0; r < 4; ++r)
                    eg[r] = __expf(-(ag[r] + bg_r[hl]));

                // att = (Q/4) @ K^T. K-dim (=C=16) zero-padded to 32.
                const bf16x8 aqf = *(const bf16x8*)&qbp[lm * SB_STR + quad * 8];
                const bf16x8 bkf = *(const bf16x8*)&kqp[lm * SB_STR + quad * 8];
                const f32x4 z4 = {0,0,0,0};
                f32x4 att = MFMA16x32(aqf, bkf, z4);

                // deferred-norm softmax: write UNNORMALIZED P~=exp(a-mx) at once;
                // the sum + combined gate/norm divide overlap the PV round-trip.
                f32x4 ex;
#pragma unroll
                for (int r = 0; r < 4; ++r) {
                    const float mx = red16_max(att[r]);
                    ex[r] = __expf(att[r] - mx);
                    qbp[(quad * 4 + r) * SB_STR + lm] = f2bf(ex[r]);  // P~ over Q buf
                }
                float sc[4];
#pragma unroll
                for (int r = 0; r < 4; ++r) {
                    const float sm = red16_sum(ex[r]);
                    sc[r] = 1.f / ((1.f + eg[r]) * sm);   // sigmoid/softmax fused, one div
                }

                // O~ = P~ @ V : A-frag of P~, B-frag from V^T rows (contiguous k=j)
                const bf16x8 apf = *(const bf16x8*)&qbp[lm * SB_STR + quad * 8];
                const bf16x8 bvf = *(const bf16x8*)&vbp[lm * SB_STR + quad * 8];
                f32x4 oc = MFMA16x32(apf, bvf, z4);

                const int hcol = (wid * 2 + hl) * 16 + lm;
#pragma unroll
                for (int r = 0; r < 4; ++r)
                    ob_s[pp][(quad * 4 + r) * ZN_STR + hcol] = f2bf(oc[r] * sc[r]);
            }
        }
        __syncthreads();   // end-B: ob visible; orders this-B zn reads vs next-A writes

        // ---- Phase C: out = O @ Wo + bo, stored DIRECTLY to global ----
#pragma unroll
        for (int pp = 0; pp < 2; ++pp) {
            bf16x8 of[4];
#pragma unroll
            for (int kb = 0; kb < 4; ++kb)
                of[kb] = *(const bf16x8*)&ob_s[pp][lm * ZN_STR + kb * 32 + quad * 8];
            float* const op0 = out + pbase + pp * DD + (long)(quad * 4) * ZSTR;
#pragma unroll
            for (int hl = 0; hl < 2; ++hl) {
                f32x4 acc = {0,0,0,0};
#pragma unroll
                for (int kb = 0; kb < 4; ++kb)
                    acc = MFMA16x32(of[kb], wo_r[hl][kb], acc);
                const int col = (wid * 2 + hl) * 16 + lm;
#pragma unroll
                for (int r = 0; r < 4; ++r)
                    op0[(long)r * ZSTR + col] = acc[r] + bo_r[hl];  // 64B contiguous/quad
            }
        }
        // no barrier here: next-iter zn write covered by end-B barrier;
        // next-iter ob write (in B) covered by next end-A barrier.
    }
}

extern "C" void kernel_launch(void* const* d_in, const int* in_sizes, int n_in,
                              void* d_out, int out_size, void* d_ws, size_t ws_size,
                              hipStream_t stream) {
    (void)in_sizes; (void)n_in; (void)out_size; (void)d_ws; (void)ws_size;
    // 512 blocks = 2 blocks/CU (unified-regfile-limited); 8192 pairs / 512 =
    // 16 iterations per block (uniform), 2 positions per iteration.
    ssattn_fused<<<dim3(512), dim3(256), 0, stream>>>(
        (const float*)d_in[0],  // z
        (const float*)d_in[1],  // ln_w
        (const float*)d_in[2],  // ln_b
        (const float*)d_in[3],  // Wq
        (const float*)d_in[4],  // Wk
        (const float*)d_in[5],  // Wv
        (const float*)d_in[6],  // Wg
        (const float*)d_in[7],  // bg
        (const float*)d_in[8],  // Wo
        (const float*)d_in[9],  // bo
        (float*)d_out);
}

// Round 7
// 286.265 us; speedup vs baseline: 1.1946x; 1.0263x over previous
//
#include <hip/hip_runtime.h>
#include <hip/hip_bf16.h>

// ssAttention fused kernel for MI355X (gfx950).
// Inputs fp32, OUTPUT fp32 (reference is an all-fp32 jnp pipeline).
// Internal compute: bf16 MFMA (16x16x32), fp32 accumulate; 2% relative gate.
// Decomposition: each pair position p=(a,b) owns a 16x128 slice (16 samples).
// One workgroup (4 waves) processes positions in a grid-stride loop:
//   LN -> Q,K,V,G proj (weights register-resident) -> per-head 16x16 attention
//   over samples -> gate -> out proj -> fp32 store.
//
// R1 (FAILED): launch_bounds(256,4) -> weight spill -> 539us. Register-
//   resident weights cap us at 2 blocks/CU (~256 unified regs).
// R2 (NEUTRAL, 183->177us/dispatch): Phase D + 2 barriers removed, z prefetch.
// R3 (COMPILE FAIL): update_dpp ctrl must be a call-site constant.
// R4 (PERF WIN, NUMERIC FAIL): DPP reductions ~15% faster; v_rcp_f32 blew the
//   ~5e-4 pre-absmax budget (post-timing check runs ~1.5x hotter).
// R5 (WIN, 177->133.5us): DPP butterflies + exact IEEE division.
//   VALU 58%, MFMA 15%, HBM 19%.
// R6 (REGRESS, 156us): 2-position batching spilled (WRITE_SIZE grew past the
//   exact output size by ~8MB = scratch). Lesson x2: any scheme extending
//   live ranges across Phase B spills. Deferred-norm itself was fine and its
//   post-timing absmax passed.
// R7: revert batching; keep (a) deferred softmax normalization: write
//   UNNORMALIZED P~=exp(a-mx) to LDS immediately, fold 1/sum into the gate
//   scale 1/((1+e^-g)*sm) -> one divide instead of two, and the PV LDS
//   round-trip overlaps the sum-reduce+divide; (b) Wq pre-scaled by
//   1/sqrt(C)=0.25 at load (exact exponent shift, bit-identical Q).

typedef short bf16x8 __attribute__((ext_vector_type(8)));
typedef float f32x4 __attribute__((ext_vector_type(4)));

#define MFMA16x32(A, B, C) __builtin_amdgcn_mfma_f32_16x16x32_bf16((A), (B), (C), 0, 0, 0)

__device__ __forceinline__ unsigned short f2bf(float f) {
    unsigned int u = __float_as_uint(f);
    u += 0x7fffu + ((u >> 16) & 1u);   // RTNE
    return (unsigned short)(u >> 16);
}

// ---- 16-lane (DPP-row) reductions, pure VALU ----
template <int CTRL>
__device__ __forceinline__ float dpp_mov16(float x) {
    return __int_as_float(__builtin_amdgcn_update_dpp(
        0, __float_as_int(x), CTRL, 0xf, 0xf, true));
}
// after each stage every lane of the combined sub-group holds the same
// partial, so mirror perms substitute for xor4/xor8 (bitwise-identical).
__device__ __forceinline__ float red16_sum(float x) {
    x += dpp_mov16<0xB1>(x);   // quad_perm [1,0,3,2]  (xor 1)
    x += dpp_mov16<0x4E>(x);   // quad_perm [2,3,0,1]  (xor 2)
    x += dpp_mov16<0x141>(x);  // row_half_mirror      (crosses quads in 8)
    x += dpp_mov16<0x140>(x);  // row_mirror           (crosses 8s in 16)
    return x;
}
__device__ __forceinline__ float red16_max(float x) {
    x = fmaxf(x, dpp_mov16<0xB1>(x));
    x = fmaxf(x, dpp_mov16<0x4E>(x));
    x = fmaxf(x, dpp_mov16<0x141>(x));
    x = fmaxf(x, dpp_mov16<0x140>(x));
    return x;
}

static constexpr int  DD     = 128;
static constexpr int  NPOS   = 128 * 128;            // 16384 pair positions
static constexpr long ZSTR   = (long)NPOS * DD;      // sample stride in elements
static constexpr int  ZN_STR = 136;  // padded stride (ushort) for 16x128 bf16 LDS bufs
static constexpr int  SB_STR = 56;   // padded stride (ushort) for 16x32 bf16 LDS bufs

__launch_bounds__(256, 2)
__global__ void ssattn_fused(const float* __restrict__ z,
                             const float* __restrict__ ln_w,
                             const float* __restrict__ ln_b,
                             const float* __restrict__ Wq,
                             const float* __restrict__ Wk,
                             const float* __restrict__ Wv,
                             const float* __restrict__ Wg,
                             const float* __restrict__ bg,
                             const float* __restrict__ Wo,
                             const float* __restrict__ bo,
                             float* __restrict__ out)
{
    __shared__ __align__(16) unsigned short zn_s[16 * ZN_STR];    // zn (bf16), A-readable
    __shared__ __align__(16) unsigned short ob_s[16 * ZN_STR];    // gated O (bf16), A-readable
    __shared__ __align__(16) unsigned short qb_s[4][16 * SB_STR]; // per-wave Q (then P~), K=32 pad
    __shared__ __align__(16) unsigned short kq_s[4][16 * SB_STR]; // per-wave K
    __shared__ __align__(16) unsigned short vb_s[4][16 * SB_STR]; // per-wave V^T
    __shared__ float lnw_s[DD];
    __shared__ float lnb_s[DD];

    const int tid  = threadIdx.x;
    const int wid  = tid >> 6;     // wave 0..3 -> heads {2w, 2w+1}
    const int lane = tid & 63;
    const int quad = lane >> 4;
    const int lm   = lane & 15;
    const int r16  = tid >> 4;     // row 0..15 for LN phase
    const int s16  = tid & 15;

    // ---- one-time setup: LN params to LDS, zero K=32 pad scratch ----
    if (tid < DD) { lnw_s[tid] = ln_w[tid]; lnb_s[tid] = ln_b[tid]; }
    for (int i = tid; i < 16 * SB_STR; i += 256) {
        qb_s[0][i] = 0; qb_s[1][i] = 0; qb_s[2][i] = 0; qb_s[3][i] = 0;
        kq_s[0][i] = 0; kq_s[1][i] = 0; kq_s[2][i] = 0; kq_s[3][i] = 0;
        vb_s[0][i] = 0; vb_s[1][i] = 0; vb_s[2][i] = 0; vb_s[3][i] = 0;
    }

    // ---- register-resident weights (fp32 -> bf16): B-frag B[k=kb*32+quad*8+j][n=col]
    //      Wq pre-scaled by 1/sqrt(C)=0.25 (exact exponent shift in bf16). ----
    bf16x8 wq_r[2][4], wk_r[2][4], wv_r[2][4], wg_r[2][4], wo_r[2][4];
    float bg_r[2], bo_r[2];
#pragma unroll
    for (int hl = 0; hl < 2; ++hl) {
        const int col = (wid * 2 + hl) * 16 + lm;
        bg_r[hl] = bg[col];
        bo_r[hl] = bo[col];
#pragma unroll
        for (int kb = 0; kb < 4; ++kb) {
            const int kbase = kb * 32 + quad * 8;
            bf16x8 a, b, c, d, e;
#pragma unroll
            for (int j = 0; j < 8; ++j) {
                const int k = kbase + j;
                a[j] = (short)f2bf(Wq[k * DD + col] * 0.25f);
                b[j] = (short)f2bf(Wk[k * DD + col]);
                c[j] = (short)f2bf(Wv[k * DD + col]);
                d[j] = (short)f2bf(Wg[k * DD + col]);
                e[j] = (short)f2bf(Wo[k * DD + col]);
            }
            wq_r[hl][kb] = a; wk_r[hl][kb] = b; wv_r[hl][kb] = c;
            wg_r[hl][kb] = d; wo_r[hl][kb] = e;
        }
    }
    __syncthreads();

    unsigned short* const qb = qb_s[wid];
    unsigned short* const kq = kq_s[wid];
    unsigned short* const vb = vb_s[wid];

    // ---- prologue: load first z-tile into registers ----
    int p = blockIdx.x;
    float4 cura, curb;
    {
        const float* zp = z + (long)r16 * ZSTR + (long)p * DD + s16 * 8;
        cura = *(const float4*)zp;
        curb = *(const float4*)(zp + 4);
    }

    for (; p < NPOS; p += gridDim.x) {
        // ---- Phase A: LayerNorm 16 z-rows (registers preloaded), store zn (bf16) ----
        {
            float x[8] = {cura.x, cura.y, cura.z, cura.w, curb.x, curb.y, curb.z, curb.w};
            float s = 0.f, ss = 0.f;
#pragma unroll
            for (int j = 0; j < 8; ++j) { s += x[j]; ss += x[j] * x[j]; }
            s  = red16_sum(s);
            ss = red16_sum(ss);
            const float mu = s * (1.f / 128.f);
            const float rs = rsqrtf(ss * (1.f / 128.f) - mu * mu + 1e-5f);
            unsigned int pk[4];
#pragma unroll
            for (int jj = 0; jj < 4; ++jj) {
                const int c0 = s16 * 8 + jj * 2;
                const unsigned short lo = f2bf((x[jj * 2]     - mu) * rs * lnw_s[c0]     + lnb_s[c0]);
                const unsigned short hi = f2bf((x[jj * 2 + 1] - mu) * rs * lnw_s[c0 + 1] + lnb_s[c0 + 1]);
                pk[jj] = (unsigned)lo | ((unsigned)hi << 16);
            }
            uint4 st; st.x = pk[0]; st.y = pk[1]; st.z = pk[2]; st.w = pk[3];
            *(uint4*)&zn_s[r16 * ZN_STR + s16 * 8] = st;
        }
        __syncthreads();   // end-A: zn_s visible; also orders prev-C ob_s reads vs this-B writes

        // ---- prefetch next iteration's z-tile (latency hides under Phase B) ----
        {
            const int pn  = p + gridDim.x;
            const int pnc = (pn < NPOS) ? pn : p;   // clamped; dead on last iter
            const float* zp2 = z + (long)r16 * ZSTR + (long)pnc * DD + s16 * 8;
            cura = *(const float4*)zp2;
            curb = *(const float4*)(zp2 + 4);
        }

        // ---- Phase B: projections (MFMA) + per-head attention ----
        bf16x8 af[4];  // A-frags of zn (A[m=lm][k=kb*32+quad*8+j])
#pragma unroll
        for (int kb = 0; kb < 4; ++kb)
            af[kb] = *(const bf16x8*)&zn_s[lm * ZN_STR + kb * 32 + quad * 8];

#pragma unroll
        for (int hl = 0; hl < 2; ++hl) {
            f32x4 aq = {0,0,0,0}, ak = {0,0,0,0}, av = {0,0,0,0}, ag = {0,0,0,0};
#pragma unroll
            for (int kb = 0; kb < 4; ++kb) {
                aq = MFMA16x32(af[kb], wq_r[hl][kb], aq);
                ak = MFMA16x32(af[kb], wk_r[hl][kb], ak);
                av = MFMA16x32(af[kb], wv_r[hl][kb], av);
                ag = MFMA16x32(af[kb], wg_r[hl][kb], ag);
            }
            // C/D layout: row = quad*4+r, col = lm. (1/sqrt(C) already in Wq.)
#pragma unroll
            for (int r = 0; r < 4; ++r) {
                const int row = quad * 4 + r;
                qb[row * SB_STR + lm] = f2bf(aq[r]);   // Q[i][c]
                kq[row * SB_STR + lm] = f2bf(ak[r]);   // K[j][c]
                vb[lm * SB_STR + row] = f2bf(av[r]);   // V^T[c][j]
            }
            float eg[4];
#pragma unroll
            for (int r = 0; r < 4; ++r)
                eg[r] = __expf(-(ag[r] + bg_r[hl]));

            // att = (Q/4) @ K^T. K-dim (=C=16) zero-padded to 32.
            const bf16x8 aqf = *(const bf16x8*)&qb[lm * SB_STR + quad * 8];
            const bf16x8 bkf = *(const bf16x8*)&kq[lm * SB_STR + quad * 8];
            const f32x4 z4 = {0,0,0,0};
            f32x4 att = MFMA16x32(aqf, bkf, z4);

            // deferred-norm softmax: write UNNORMALIZED P~=exp(a-mx) immediately;
            // the sum-reduce + fused gate/norm divide overlap the PV round-trip.
            f32x4 ex;
#pragma unroll
            for (int r = 0; r < 4; ++r) {
                const float mx = red16_max(att[r]);
                ex[r] = __expf(att[r] - mx);
                qb[(quad * 4 + r) * SB_STR + lm] = f2bf(ex[r]);  // P~ over Q buf
            }
            float sc[4];
#pragma unroll
            for (int r = 0; r < 4; ++r) {
                const float sm = red16_sum(ex[r]);
                sc[r] = 1.f / ((1.f + eg[r]) * sm);   // sigmoid+softmax fused, one div
            }

            // O~ = P~ @ V : A-frag of P~, B-frag from V^T rows (contiguous k=j)
            const bf16x8 apf = *(const bf16x8*)&qb[lm * SB_STR + quad * 8];
            const bf16x8 bvf = *(const bf16x8*)&vb[lm * SB_STR + quad * 8];
            f32x4 oc = MFMA16x32(apf, bvf, z4);

            const int hcol = (wid * 2 + hl) * 16 + lm;
#pragma unroll
            for (int r = 0; r < 4; ++r)
                ob_s[(quad * 4 + r) * ZN_STR + hcol] = f2bf(oc[r] * sc[r]);
        }
        __syncthreads();   // end-B: ob_s visible; also orders this-B zn_s reads vs next-A writes

        // ---- Phase C: out = O @ Wo + bo, stored DIRECTLY to global ----
        bf16x8 of[4];
#pragma unroll
        for (int kb = 0; kb < 4; ++kb)
            of[kb] = *(const bf16x8*)&ob_s[lm * ZN_STR + kb * 32 + quad * 8];
        float* const op0 = out + (long)p * DD + (long)(quad * 4) * ZSTR;
#pragma unroll
        for (int hl = 0; hl < 2; ++hl) {
            f32x4 acc = {0,0,0,0};
#pragma unroll
            for (int kb = 0; kb < 4; ++kb)
                acc = MFMA16x32(of[kb], wo_r[hl][kb], acc);
            const int col = (wid * 2 + hl) * 16 + lm;
#pragma unroll
            for (int r = 0; r < 4; ++r)
                op0[(long)r * ZSTR + col] = acc[r] + bo_r[hl];  // 64B contiguous per quad
        }
        // no barrier here: next-iter zn_s write is covered by end-B barrier;
        // next-iter ob_s write (in B) is covered by next end-A barrier.
    }
}

extern "C" void kernel_launch(void* const* d_in, const int* in_sizes, int n_in,
                              void* d_out, int out_size, void* d_ws, size_t ws_size,
                              hipStream_t stream) {
    (void)in_sizes; (void)n_in; (void)out_size; (void)d_ws; (void)ws_size;
    // 512 blocks = 2 blocks/CU (unified-regfile-limited); 16384/512 = 32
    // positions per block (uniform).
    ssattn_fused<<<dim3(512), dim3(256), 0, stream>>>(
        (const float*)d_in[0],  // z
        (const float*)d_in[1],  // ln_w
        (const float*)d_in[2],  // ln_b
        (const float*)d_in[3],  // Wq
        (const float*)d_in[4],  // Wk
        (const float*)d_in[5],  // Wv
        (const float*)d_in[6],  // Wg
        (const float*)d_in[7],  // bg
        (const float*)d_in[8],  // Wo
        (const float*)d_in[9],  // bo
        (float*)d_out);
}

// Round 9
// 285.646 us; speedup vs baseline: 1.1972x; 1.0022x over previous
//
#include <hip/hip_runtime.h>
#include <hip/hip_bf16.h>

// ssAttention fused kernel for MI355X (gfx950).
// Inputs fp32, OUTPUT fp32 (reference is an all-fp32 jnp pipeline).
// Internal compute: bf16 MFMA (16x16x32), fp32 accumulate; 2% relative gate.
// Decomposition: each pair position p=(a,b) owns a 16x128 slice (16 samples).
// One workgroup (4 waves) processes positions in a grid-stride loop:
//   LN -> Q,K,V,G proj (weights register-resident) -> per-head 16x16 attention
//   over samples -> gate -> out proj -> fp32 store.
//
// R1 (FAILED): launch_bounds(256,4) -> weight spill -> 539us. Register-
//   resident weights cap us at 2 blocks/CU (~256 unified regs).
// R2 (NEUTRAL, 183->177us/dispatch): Phase D + 2 barriers removed, z prefetch.
// R3 (COMPILE FAIL): update_dpp ctrl must be a call-site constant.
// R4 (PERF WIN, NUMERIC FAIL): DPP reductions ~15% faster; v_rcp_f32 blew the
//   ~5e-4 pre-absmax budget (post-timing check runs ~1.5x hotter).
// R5 (WIN, 177->133.5us): DPP butterflies + exact IEEE division.
// R6 (REGRESS, 156us): 2-position batching spilled. Live-range growth
//   across Phase B spills (scratch shows up as WRITE_SIZE > output size).
// R7 (WIN, 133.5->122.3us): deferred softmax norm (unnormalized P~ to LDS,
//   1/sum folded into gate divide) + Wq pre-scaled by 0.25.
//   Counters: VALU 54.6%, MFMA 16%, HBM 21%.
// R8 (NUMERIC FAIL, NaN): bundled v_cvt_pk_bf16_f32 inline asm + split-LDS.
//   Split audited bit-identical; the hand-written cvt asm is the prime
//   suspect (m240 in the corpus: "don't hand-write cvt_pk"). Lesson: one
//   variable per round when numerics are involved.
// R9: R7 arithmetic EXACTLY (software f2bf everywhere) + the provably-safe
//   subset of R8: (a) per-hl split LDS scratch (qb/kq/vb x2) so the hl=0 and
//   hl=1 chains' DS ops aren't falsely ordered and their LDS round-trips
//   overlap; (b) V^T written as one ds_write_b64 (software-packed) instead
//   of 4 ds_write_b16. Verification: absmax must be EXACTLY 4.978e-4.

typedef short bf16x8 __attribute__((ext_vector_type(8)));
typedef float f32x4 __attribute__((ext_vector_type(4)));

#define MFMA16x32(A, B, C) __builtin_amdgcn_mfma_f32_16x16x32_bf16((A), (B), (C), 0, 0, 0)

__device__ __forceinline__ unsigned short f2bf(float f) {
    unsigned int u = __float_as_uint(f);
    u += 0x7fffu + ((u >> 16) & 1u);   // RTNE
    return (unsigned short)(u >> 16);
}
__device__ __forceinline__ unsigned pack2_bf16(float lo, float hi) {
    return (unsigned)f2bf(lo) | ((unsigned)f2bf(hi) << 16);
}

// ---- 16-lane (DPP-row) reductions, pure VALU ----
template <int CTRL>
__device__ __forceinline__ float dpp_mov16(float x) {
    return __int_as_float(__builtin_amdgcn_update_dpp(
        0, __float_as_int(x), CTRL, 0xf, 0xf, true));
}
// after each stage every lane of the combined sub-group holds the same
// partial, so mirror perms substitute for xor4/xor8 (bitwise-identical).
__device__ __forceinline__ float red16_sum(float x) {
    x += dpp_mov16<0xB1>(x);   // quad_perm [1,0,3,2]  (xor 1)
    x += dpp_mov16<0x4E>(x);   // quad_perm [2,3,0,1]  (xor 2)
    x += dpp_mov16<0x141>(x);  // row_half_mirror      (crosses quads in 8)
    x += dpp_mov16<0x140>(x);  // row_mirror           (crosses 8s in 16)
    return x;
}
__device__ __forceinline__ float red16_max(float x) {
    x = fmaxf(x, dpp_mov16<0xB1>(x));
    x = fmaxf(x, dpp_mov16<0x4E>(x));
    x = fmaxf(x, dpp_mov16<0x141>(x));
    x = fmaxf(x, dpp_mov16<0x140>(x));
    return x;
}

static constexpr int  DD     = 128;
static constexpr int  NPOS   = 128 * 128;            // 16384 pair positions
static constexpr long ZSTR   = (long)NPOS * DD;      // sample stride in elements
static constexpr int  ZN_STR = 136;  // padded stride (ushort) for 16x128 bf16 LDS bufs
static constexpr int  SB_STR = 56;   // padded stride (ushort) for 16x32 bf16 LDS bufs

__launch_bounds__(256, 2)
__global__ void ssattn_fused(const float* __restrict__ z,
                             const float* __restrict__ ln_w,
                             const float* __restrict__ ln_b,
                             const float* __restrict__ Wq,
                             const float* __restrict__ Wk,
                             const float* __restrict__ Wv,
                             const float* __restrict__ Wg,
                             const float* __restrict__ bg,
                             const float* __restrict__ Wo,
                             const float* __restrict__ bo,
                             float* __restrict__ out)
{
    __shared__ __align__(16) unsigned short zn_s[16 * ZN_STR];       // zn (bf16)
    __shared__ __align__(16) unsigned short ob_s[16 * ZN_STR];       // gated O (bf16)
    __shared__ __align__(16) unsigned short qb_s[4][2][16 * SB_STR]; // per-wave/hl Q->P~
    __shared__ __align__(16) unsigned short kq_s[4][2][16 * SB_STR]; // per-wave/hl K
    __shared__ __align__(16) unsigned short vb_s[4][2][16 * SB_STR]; // per-wave/hl V^T
    __shared__ float lnw_s[DD];
    __shared__ float lnb_s[DD];

    const int tid  = threadIdx.x;
    const int wid  = tid >> 6;     // wave 0..3 -> heads {2w, 2w+1}
    const int lane = tid & 63;
    const int quad = lane >> 4;
    const int lm   = lane & 15;
    const int r16  = tid >> 4;     // row 0..15 for LN phase
    const int s16  = tid & 15;

    // ---- one-time setup: LN params to LDS, zero K=32 pad scratch ----
    if (tid < DD) { lnw_s[tid] = ln_w[tid]; lnb_s[tid] = ln_b[tid]; }
    for (int i = tid; i < 4 * 2 * 16 * SB_STR; i += 256) {
        ((unsigned short*)qb_s)[i] = 0;
        ((unsigned short*)kq_s)[i] = 0;
        ((unsigned short*)vb_s)[i] = 0;
    }

    // ---- register-resident weights (fp32 -> bf16): B-frag B[k=kb*32+quad*8+j][n=col]
    //      Wq pre-scaled by 1/sqrt(C)=0.25 (exact exponent shift in bf16). ----
    bf16x8 wq_r[2][4], wk_r[2][4], wv_r[2][4], wg_r[2][4], wo_r[2][4];
    float bg_r[2], bo_r[2];
#pragma unroll
    for (int hl = 0; hl < 2; ++hl) {
        const int col = (wid * 2 + hl) * 16 + lm;
        bg_r[hl] = bg[col];
        bo_r[hl] = bo[col];
#pragma unroll
        for (int kb = 0; kb < 4; ++kb) {
            const int kbase = kb * 32 + quad * 8;
            bf16x8 a, b, c, d, e;
#pragma unroll
            for (int j = 0; j < 8; ++j) {
                const int k = kbase + j;
                a[j] = (short)f2bf(Wq[k * DD + col] * 0.25f);
                b[j] = (short)f2bf(Wk[k * DD + col]);
                c[j] = (short)f2bf(Wv[k * DD + col]);
                d[j] = (short)f2bf(Wg[k * DD + col]);
                e[j] = (short)f2bf(Wo[k * DD + col]);
            }
            wq_r[hl][kb] = a; wk_r[hl][kb] = b; wv_r[hl][kb] = c;
            wg_r[hl][kb] = d; wo_r[hl][kb] = e;
        }
    }
    __syncthreads();

    // ---- prologue: load first z-tile into registers ----
    int p = blockIdx.x;
    float4 cura, curb;
    {
        const float* zp = z + (long)r16 * ZSTR + (long)p * DD + s16 * 8;
        cura = *(const float4*)zp;
        curb = *(const float4*)(zp + 4);
    }

    for (; p < NPOS; p += gridDim.x) {
        // ---- Phase A: LayerNorm 16 z-rows (registers preloaded), store zn (bf16) ----
        {
            float x[8] = {cura.x, cura.y, cura.z, cura.w, curb.x, curb.y, curb.z, curb.w};
            float s = 0.f, ss = 0.f;
#pragma unroll
            for (int j = 0; j < 8; ++j) { s += x[j]; ss += x[j] * x[j]; }
            s  = red16_sum(s);
            ss = red16_sum(ss);
            const float mu = s * (1.f / 128.f);
            const float rs = rsqrtf(ss * (1.f / 128.f) - mu * mu + 1e-5f);
            unsigned int pk[4];
#pragma unroll
            for (int jj = 0; jj < 4; ++jj) {
                const int c0 = s16 * 8 + jj * 2;
                const float lo = (x[jj * 2]     - mu) * rs * lnw_s[c0]     + lnb_s[c0];
                const float hi = (x[jj * 2 + 1] - mu) * rs * lnw_s[c0 + 1] + lnb_s[c0 + 1];
                pk[jj] = pack2_bf16(lo, hi);
            }
            uint4 st; st.x = pk[0]; st.y = pk[1]; st.z = pk[2]; st.w = pk[3];
            *(uint4*)&zn_s[r16 * ZN_STR + s16 * 8] = st;
        }
        __syncthreads();   // end-A: zn_s visible; also orders prev-C ob_s reads vs this-B writes

        // ---- prefetch next iteration's z-tile (latency hides under Phase B) ----
        {
            const int pn  = p + gridDim.x;
            const int pnc = (pn < NPOS) ? pn : p;   // clamped; dead on last iter
            const float* zp2 = z + (long)r16 * ZSTR + (long)pnc * DD + s16 * 8;
            cura = *(const float4*)zp2;
            curb = *(const float4*)(zp2 + 4);
        }

        // ---- Phase B: projections (MFMA) + per-head attention ----
        bf16x8 af[4];  // A-frags of zn (A[m=lm][k=kb*32+quad*8+j])
#pragma unroll
        for (int kb = 0; kb < 4; ++kb)
            af[kb] = *(const bf16x8*)&zn_s[lm * ZN_STR + kb * 32 + quad * 8];

#pragma unroll
        for (int hl = 0; hl < 2; ++hl) {
            unsigned short* const qbp = qb_s[wid][hl];
            unsigned short* const kqp = kq_s[wid][hl];
            unsigned short* const vbp = vb_s[wid][hl];

            f32x4 aq = {0,0,0,0}, ak = {0,0,0,0}, av = {0,0,0,0}, ag = {0,0,0,0};
#pragma unroll
            for (int kb = 0; kb < 4; ++kb) {
                aq = MFMA16x32(af[kb], wq_r[hl][kb], aq);
                ak = MFMA16x32(af[kb], wk_r[hl][kb], ak);
                av = MFMA16x32(af[kb], wv_r[hl][kb], av);
                ag = MFMA16x32(af[kb], wg_r[hl][kb], ag);
            }
            // C/D layout: row = quad*4+r, col = lm. (1/sqrt(C) already in Wq.)
#pragma unroll
            for (int r = 0; r < 4; ++r) {
                const int row = quad * 4 + r;
                qbp[row * SB_STR + lm] = f2bf(aq[r]);   // Q[i][c]
                kqp[row * SB_STR + lm] = f2bf(ak[r]);   // K[j][c]
            }
            // V^T[c=lm][j=quad*4+r]: 4 consecutive shorts -> 1 ds_write_b64
            {
                uint2 vv;
                vv.x = pack2_bf16(av[0], av[1]);
                vv.y = pack2_bf16(av[2], av[3]);
                *(uint2*)&vbp[lm * SB_STR + quad * 4] = vv;
            }
            float eg[4];
#pragma unroll
            for (int r = 0; r < 4; ++r)
                eg[r] = __expf(-(ag[r] + bg_r[hl]));

            // att = (Q/4) @ K^T. K-dim (=C=16) zero-padded to 32.
            const bf16x8 aqf = *(const bf16x8*)&qbp[lm * SB_STR + quad * 8];
            const bf16x8 bkf = *(const bf16x8*)&kqp[lm * SB_STR + quad * 8];
            const f32x4 z4 = {0,0,0,0};
            f32x4 att = MFMA16x32(aqf, bkf, z4);

            // deferred-norm softmax: write UNNORMALIZED P~=exp(a-mx) immediately;
            // the sum-reduce + fused gate/norm divide overlap the PV round-trip.
            f32x4 ex;
#pragma unroll
            for (int r = 0; r < 4; ++r) {
                const float mx = red16_max(att[r]);
                ex[r] = __expf(att[r] - mx);
                qbp[(quad * 4 + r) * SB_STR + lm] = f2bf(ex[r]);  // P~ over Q buf
            }
            float sc[4];
#pragma unroll
            for (int r = 0; r < 4; ++r) {
                const float sm = red16_sum(ex[r]);
                sc[r] = 1.f / ((1.f + eg[r]) * sm);   // sigmoid+softmax fused, one div
            }

            // O~ = P~ @ V : A-frag of P~, B-frag from V^T rows (contiguous k=j)
            const bf16x8 apf = *(const bf16x8*)&qbp[lm * SB_STR + quad * 8];
            const bf16x8 bvf = *(const bf16x8*)&vbp[lm * SB_STR + quad * 8];
            f32x4 oc = MFMA16x32(apf, bvf, z4);

            const int hcol = (wid * 2 + hl) * 16 + lm;
#pragma unroll
            for (int r = 0; r < 4; ++r)
                ob_s[(quad * 4 + r) * ZN_STR + hcol] = f2bf(oc[r] * sc[r]);
        }
        __syncthreads();   // end-B: ob_s visible; also orders this-B zn_s reads vs next-A writes

        // ---- Phase C: out = O @ Wo + bo, stored DIRECTLY to global ----
        bf16x8 of[4];
#pragma unroll
        for (int kb = 0; kb < 4; ++kb)
            of[kb] = *(const bf16x8*)&ob_s[lm * ZN_STR + kb * 32 + quad * 8];
        float* const op0 = out + (long)p * DD + (long)(quad * 4) * ZSTR;
#pragma unroll
        for (int hl = 0; hl < 2; ++hl) {
            f32x4 acc = {0,0,0,0};
#pragma unroll
            for (int kb = 0; kb < 4; ++kb)
                acc = MFMA16x32(of[kb], wo_r[hl][kb], acc);
            const int col = (wid * 2 + hl) * 16 + lm;
#pragma unroll
            for (int r = 0; r < 4; ++r)
                op0[(long)r * ZSTR + col] = acc[r] + bo_r[hl];  // 64B contiguous per quad
        }
        // no barrier here: next-iter zn_s write is covered by end-B barrier;
        // next-iter ob_s write (in B) is covered by next end-A barrier.
    }
}

extern "C" void kernel_launch(void* const* d_in, const int* in_sizes, int n_in,
                              void* d_out, int out_size, void* d_ws, size_t ws_size,
                              hipStream_t stream) {
    (void)in_sizes; (void)n_in; (void)out_size; (void)d_ws; (void)ws_size;
    // 512 blocks = 2 blocks/CU (unified-regfile-limited); 16384/512 = 32
    // positions per block (uniform).
    ssattn_fused<<<dim3(512), dim3(256), 0, stream>>>(
        (const float*)d_in[0],  // z
        (const float*)d_in[1],  // ln_w
        (const float*)d_in[2],  // ln_b
        (const float*)d_in[3],  // Wq
        (const float*)d_in[4],  // Wk
        (const float*)d_in[5],  // Wv
        (const float*)d_in[6],  // Wg
        (const float*)d_in[7],  // bg
        (const float*)d_in[8],  // Wo
        (const float*)d_in[9],  // bo
        (float*)d_out);
}